// Round 4
// baseline (404.440 us; speedup 1.0000x reference)
//
#include <hip/hip_runtime.h>
#include <hip/hip_bf16.h>
#include <math.h>

// B=2048 segs x S=512 tok, D=64. 4-layer tanh MLP -> logit/token -> ragged
// per-segment softmax. Global-max subtraction cancels in e/denom; we use the
// per-segment max (mathematically identical after normalization).
//
// MFMA formulation (tokens = N dimension, "swapped"):
//   z1 = W1^T(128x64) @ x^T(64xN)   -> 8 M-tiles x 2 K-steps
//   z2 = W2^T(64x128) @ h1(128xN)   -> 4 M-tiles x 4 K-steps
//   z3 = W3^T(16x64)  @ h2(64xN)    -> 1 M-tile  x 2 K-steps
//   logit = W4 . h3 + b4            -> VALU + shfl_xor reduce
// 16x16x32 bf16 fragment mappings (HW-verified, learn_hip m89/m91):
//   A: row = lane&15, k = (lane>>4)*8 + j     B: col = lane&15, same k
//   D: col = lane&15, row = (lane>>4)*4 + reg
// Per-layer D -> tanh -> bf16 -> wave-PRIVATE LDS slab -> next B-frags
// (ds_read_b128, 16B contiguous). No __syncthreads in the chunk loop.
//
// R3 fix: harness reads the ENTIRE d_out as float32 and slices the tuple;
// Output 1 (sizes) must be written as FLOAT VALUES, not raw int32 bits.
// (R2 bench: output 0 passed -> MLP+softmax numerics verified; output 1
// absmax was exactly 512 = |512 - bitcast_f32(512i)~0|.)

#define D_IN 64
#define H1 128
#define H2 64
#define H3 16
#define CHUNKS 8
#define BLK_TOK 512            // tokens per block (8 chunks x 64)
#define NPACK 17408            // packed weight elements (W1 8192, W2 8192, W3 1024)
#define WS_OFFS_BYTES 36864    // offs[] location in d_ws (packed weights use 34816 B)

typedef __attribute__((ext_vector_type(8))) short bf16x8;
typedef __attribute__((ext_vector_type(4))) float f32x4;
typedef __attribute__((ext_vector_type(4))) short s16x4;

__device__ __forceinline__ short f2bs(float f) {
    __hip_bfloat16 h = __float2bfloat16(f);   // RNE
    short s;
    __builtin_memcpy(&s, &h, sizeof(short));
    return s;
}

__device__ __forceinline__ float fast_tanh(float v) {
    // tanh(v) = 1 - 2/(exp(2v)+1); saturates correctly at +-inf, NaN-free.
    float e2 = __expf(2.0f * v);
    return fmaf(-2.0f, __builtin_amdgcn_rcpf(e2 + 1.0f), 1.0f);
}

// ---------------------------------------------------------------------------
// Prep: block 0 scans sizes -> offs[B+1]; blocks 1..68 pack W1/W2/W3 into
// bf16 A-fragment order: wpack[((frag*64)+lane)*8 + j], frag 0..33.
// ---------------------------------------------------------------------------
__global__ __launch_bounds__(256) void prep_kernel(
    const int* __restrict__ sizes, int nseg, int* __restrict__ offs,
    const float* __restrict__ W1, const float* __restrict__ W2,
    const float* __restrict__ W3, short* __restrict__ wpack,
    float* __restrict__ sizes_out) {
    int tid = threadIdx.x;
    if (blockIdx.x == 0) {
        __shared__ int part[256];
        int per = (nseg + 255) / 256;
        int base = tid * per;
        int s = 0;
        for (int i = 0; i < per; ++i) {
            int k = base + i;
            s += (k < nseg) ? sizes[k] : 0;
        }
        part[tid] = s;
        __syncthreads();
        for (int d = 1; d < 256; d <<= 1) {
            int v = (tid >= d) ? part[tid - d] : 0;
            __syncthreads();
            part[tid] += v;
            __syncthreads();
        }
        int run = part[tid] - s;
        for (int i = 0; i < per; ++i) {
            int k = base + i;
            if (k < nseg) {
                offs[k] = run;
                run += sizes[k];
                sizes_out[k] = (float)sizes[k];   // tuple output 1, as f32 values
            }
        }
        if (tid == 255) offs[nseg] = run;
    } else {
        int idx = (blockIdx.x - 1) * 256 + tid;
        if (idx < NPACK) {
            int j = idx & 7, lane = (idx >> 3) & 63, f = idx >> 9;
            int g = lane >> 4, c = lane & 15;
            float v;
            if (f < 16) {            // W1^T tiles: m 0..7, ks 0..1 (f = 2m+ks)
                int m = f >> 1, ks = f & 1;
                v = W1[(ks * 32 + g * 8 + j) * H1 + m * 16 + c];
            } else if (f < 32) {     // W2^T tiles: m 0..3, ks 0..3 (f-16 = 4m+ks)
                int f2 = f - 16, m = f2 >> 2, ks = f2 & 3;
                v = W2[(ks * 32 + g * 8 + j) * H2 + m * 16 + c];
            } else {                 // W3^T tile: ks 0..1
                int ks = f - 32;
                v = W3[(ks * 32 + g * 8 + j) * H3 + c];
            }
            wpack[idx] = f2bs(v);
        }
    }
}

// ---------------------------------------------------------------------------
// Fused MFMA MLP. 256 thr = 4 waves; wave handles 16 tokens/chunk, 8 chunks.
// launch_bounds(256,2): cap VGPR at 256 -> >=2 waves/SIMD for HBM saturation.
// ---------------------------------------------------------------------------
__global__ __launch_bounds__(256, 2) void mlp_mfma(
    const float* __restrict__ x, const short* __restrict__ wpack,
    const float* __restrict__ b1, const float* __restrict__ b2,
    const float* __restrict__ b3, const float* __restrict__ W4,
    const float* __restrict__ b4, float* __restrict__ logits, int total) {

    __shared__ float biasLds[192];       // b1[0..127], b2[128..191]
    __shared__ short hslab[4][3328];     // per-wave: h1 [16][136] @0, h2 [16][72] @2176

    int tid = threadIdx.x;
    int lane = tid & 63;
    int w = tid >> 6;
    int g = lane >> 4;   // 0..3 (k-group / D-row group)
    int c = lane & 15;   // token column within wave tile

    if (tid < 192) biasLds[tid] = (tid < 128) ? b1[tid] : b2[tid - 128];
    __syncthreads();     // only barrier; chunk loop uses wave-private LDS

    // Weight A-fragments -> VGPRs (identical for all waves; L2-broadcast).
    const bf16x8* wp = (const bf16x8*)wpack;
    bf16x8 w1f[16], w2f[16], w3f0, w3f1;
#pragma unroll
    for (int f = 0; f < 16; ++f) w1f[f] = wp[f * 64 + lane];
#pragma unroll
    for (int f = 0; f < 16; ++f) w2f[f] = wp[(16 + f) * 64 + lane];
    w3f0 = wp[32 * 64 + lane];
    w3f1 = wp[33 * 64 + lane];

    f32x4 w4v = *(const f32x4*)(W4 + 4 * g);   // lane's 4 h3 rows
    f32x4 b3v = *(const f32x4*)(b3 + 4 * g);
    float b4s = b4[0];

    short* h1s = &hslab[w][0];
    short* h2s = &hslab[w][2176];

    int tok0 = blockIdx.x * BLK_TOK + w * 16 + c;

    // Preload chunk 0 x-rows: lane reads feats [8g..8g+7] and [32+8g..+7].
    f32x4 xa0, xa1, xb0, xb1;
    {
        int tl = (tok0 < total) ? tok0 : (total - 1);
        const f32x4* row = (const f32x4*)(x + (size_t)tl * D_IN);
        xa0 = row[2 * g];     xa1 = row[2 * g + 1];
        xb0 = row[8 + 2 * g]; xb1 = row[9 + 2 * g];
    }

#pragma unroll 1
    for (int ch = 0; ch < CHUNKS; ++ch) {
        // Convert current chunk to bf16 B-fragments (frees the f32 regs)...
        bf16x8 xA, xB;
#pragma unroll
        for (int i = 0; i < 4; ++i) {
            xA[i] = f2bs(xa0[i]); xA[4 + i] = f2bs(xa1[i]);
            xB[i] = f2bs(xb0[i]); xB[4 + i] = f2bs(xb1[i]);
        }
        // ...then immediately issue next chunk's loads (WAR-pipelined:
        // HBM latency hides under this chunk's MFMA/VALU work).
        if (ch + 1 < CHUNKS) {
            int tok = tok0 + (ch + 1) * 64;
            int tl = (tok < total) ? tok : (total - 1);
            const f32x4* row = (const f32x4*)(x + (size_t)tl * D_IN);
            xa0 = row[2 * g];     xa1 = row[2 * g + 1];
            xb0 = row[8 + 2 * g]; xb1 = row[9 + 2 * g];
        }

        // ---- Layer 1: 8 M-tiles x K=64 ----
#pragma unroll
        for (int m = 0; m < 8; ++m) {
            f32x4 a = {0.f, 0.f, 0.f, 0.f};
            a = __builtin_amdgcn_mfma_f32_16x16x32_bf16(w1f[2 * m], xA, a, 0, 0, 0);
            a = __builtin_amdgcn_mfma_f32_16x16x32_bf16(w1f[2 * m + 1], xB, a, 0, 0, 0);
            f32x4 bv = *(const f32x4*)&biasLds[m * 16 + 4 * g];  // group-uniform
            s16x4 hh;
#pragma unroll
            for (int r = 0; r < 4; ++r) hh[r] = f2bs(fast_tanh(a[r] + bv[r]));
            // rows 16m+4g..+3 for token c, contiguous -> ds_write_b64
            *(s16x4*)&h1s[c * 136 + m * 16 + 4 * g] = hh;
        }

        // ---- Layer 2: 4 M-tiles x K=128 ----
        bf16x8 p0 = *(const bf16x8*)&h1s[c * 136 + 0 * 32 + 8 * g];
        bf16x8 p1 = *(const bf16x8*)&h1s[c * 136 + 1 * 32 + 8 * g];
        bf16x8 p2 = *(const bf16x8*)&h1s[c * 136 + 2 * 32 + 8 * g];
        bf16x8 p3 = *(const bf16x8*)&h1s[c * 136 + 3 * 32 + 8 * g];
#pragma unroll
        for (int m = 0; m < 4; ++m) {
            f32x4 a = {0.f, 0.f, 0.f, 0.f};
            a = __builtin_amdgcn_mfma_f32_16x16x32_bf16(w2f[4 * m + 0], p0, a, 0, 0, 0);
            a = __builtin_amdgcn_mfma_f32_16x16x32_bf16(w2f[4 * m + 1], p1, a, 0, 0, 0);
            a = __builtin_amdgcn_mfma_f32_16x16x32_bf16(w2f[4 * m + 2], p2, a, 0, 0, 0);
            a = __builtin_amdgcn_mfma_f32_16x16x32_bf16(w2f[4 * m + 3], p3, a, 0, 0, 0);
            f32x4 bv = *(const f32x4*)&biasLds[128 + m * 16 + 4 * g];
            s16x4 hh;
#pragma unroll
            for (int r = 0; r < 4; ++r) hh[r] = f2bs(fast_tanh(a[r] + bv[r]));
            *(s16x4*)&h2s[c * 72 + m * 16 + 4 * g] = hh;
        }

        // ---- Layer 3: 1 M-tile x K=64 ----
        bf16x8 q0 = *(const bf16x8*)&h2s[c * 72 + 0 * 32 + 8 * g];
        bf16x8 q1 = *(const bf16x8*)&h2s[c * 72 + 1 * 32 + 8 * g];
        f32x4 a3 = {0.f, 0.f, 0.f, 0.f};
        a3 = __builtin_amdgcn_mfma_f32_16x16x32_bf16(w3f0, q0, a3, 0, 0, 0);
        a3 = __builtin_amdgcn_mfma_f32_16x16x32_bf16(w3f1, q1, a3, 0, 0, 0);

        // ---- Layer 4: dot(h3, W4) via partial per k-group + xor-reduce ----
        float pl = 0.f;
#pragma unroll
        for (int r = 0; r < 4; ++r)
            pl = fmaf(fast_tanh(a3[r] + b3v[r]), w4v[r], pl);
        pl += __shfl_xor(pl, 16, 64);
        pl += __shfl_xor(pl, 32, 64);

        int tok = tok0 + ch * 64;
        if (g == 0 && tok < total) logits[tok] = pl + b4s;  // 16-lane 64B store
    }
}

// ---------------------------------------------------------------------------
// Per-segment softmax, in place over logits. One block per segment.
// ---------------------------------------------------------------------------
__global__ __launch_bounds__(256) void softmax_kernel(
    float* __restrict__ out, const int* __restrict__ offs,
    const int* __restrict__ sizes) {
    __shared__ float smax[4];
    __shared__ float ssum[4];

    int b = blockIdx.x;
    int off = offs[b];
    int n = sizes[b];
    int tid = threadIdx.x;
    int lane = tid & 63;
    int wid = tid >> 6;

    float m = -INFINITY;
    for (int i = tid; i < n; i += blockDim.x) m = fmaxf(m, out[off + i]);
#pragma unroll
    for (int d = 32; d >= 1; d >>= 1) m = fmaxf(m, __shfl_down(m, d, 64));
    if (lane == 0) smax[wid] = m;
    __syncthreads();
    float gm = fmaxf(fmaxf(smax[0], smax[1]), fmaxf(smax[2], smax[3]));

    float s = 0.0f;
    for (int i = tid; i < n; i += blockDim.x) {
        float e = __expf(out[off + i] - gm);
        out[off + i] = e;
        s += e;
    }
#pragma unroll
    for (int d = 32; d >= 1; d >>= 1) s += __shfl_down(s, d, 64);
    if (lane == 0) ssum[wid] = s;
    __syncthreads();
    float denom = ssum[0] + ssum[1] + ssum[2] + ssum[3];

    float inv = 1.0f / denom;
    for (int i = tid; i < n; i += blockDim.x) out[off + i] *= inv;
}

// ---------------------------------------------------------------------------
extern "C" void kernel_launch(void* const* d_in, const int* in_sizes, int n_in,
                              void* d_out, int out_size, void* d_ws,
                              size_t ws_size, hipStream_t stream) {
    const float* x   = (const float*)d_in[0];
    const int* sizes = (const int*)d_in[1];
    const float* W1  = (const float*)d_in[2];
    const float* b1  = (const float*)d_in[3];
    const float* W2  = (const float*)d_in[4];
    const float* b2  = (const float*)d_in[5];
    const float* W3  = (const float*)d_in[6];
    const float* b3  = (const float*)d_in[7];
    const float* W4  = (const float*)d_in[8];
    const float* b4  = (const float*)d_in[9];

    int total = in_sizes[0] / D_IN;   // 1048576
    int B     = in_sizes[1];          // 2048

    float* out  = (float*)d_out;
    short* wpck = (short*)d_ws;                          // 34816 B packed weights
    int* offs   = (int*)((char*)d_ws + WS_OFFS_BYTES);   // B+1 ints

    // Prep: scan + sizes->f32 tail (block 0) + weight packing (blocks 1..68).
    prep_kernel<<<1 + (NPACK + 255) / 256, 256, 0, stream>>>(
        sizes, B, offs, W1, W2, W3, wpck, out + total);

    int nblk = (total + BLK_TOK - 1) / BLK_TOK;          // 2048
    mlp_mfma<<<nblk, 256, 0, stream>>>(x, wpck, b1, b2, b3, W4, b4, out, total);

    softmax_kernel<<<B, 256, 0, stream>>>(out, offs, sizes);
}